// Round 11
// baseline (358.481 us; speedup 1.0000x reference)
//
#include <hip/hip_runtime.h>
#include <hip/hip_bf16.h>
#include <math.h>

#define N_NODES 50000
#define N_EDGES 850000
#define IN_DIM  256
#define HD      128      // H1*D
#define H1      4
#define D       32
#define NC      40       // num classes
#define SLOPE   0.2f
#define EPS_BN  1e-5f

#define NBIN    782      // ceil(50000/64) destination bins of 64 nodes
#define BCAP    1536     // compact slots per bin (mean 1088, sigma ~33)
#define NREP    32       // cursor replicas per bin
#define RCAP    160      // slots per (bin,replica). rep=blockIdx&31 -> loop-cells
                         // get 64 loops + ~32 random = 96 mean, sigma 5.7 -> 11sigma.
                         // blockIdx-rep confines each cell to ONE XCD (no L2 ping-pong).
#define NWAVE   4        // waves per 256-thread block (binsort strides by THIS)

typedef __attribute__((ext_vector_type(8))) short bf16x8;
typedef __attribute__((ext_vector_type(4))) float f32x4;
typedef unsigned long long u64;

__device__ __forceinline__ unsigned short f2bf(float x) {
    union { float f; unsigned u; } v; v.f = x;
    unsigned r = v.u + 0x7FFF + ((v.u >> 16) & 1);   // RNE
    return (unsigned short)(r >> 16);
}
__device__ __forceinline__ float bf2f(unsigned short h) {
    union { unsigned u; float f; } v; v.u = ((unsigned)h) << 16;
    return v.f;
}
__device__ __forceinline__ uint4 pack8(float a0,float a1,float a2,float a3,
                                       float a4,float a5,float a6,float a7) {
    uint4 p;
    p.x = f2bf(a0) | ((unsigned)f2bf(a1) << 16);
    p.y = f2bf(a2) | ((unsigned)f2bf(a3) << 16);
    p.z = f2bf(a4) | ((unsigned)f2bf(a5) << 16);
    p.w = f2bf(a6) | ((unsigned)f2bf(a7) << 16);
    return p;
}

// chunk-swizzled [rows][32] bf16 tile: 4 chunks of 8 bf16 per row (64B rows).
__device__ __forceinline__ int tile32_addr(int row, int chunk) {
    return row * 32 + ((chunk ^ ((row >> 1) & 3)) << 3);
}

// ---------------------------------------------------------------------------
// binscatter (+ weight cvt): edge e -> tmp[(bin*NREP + (blockIdx&31))*RCAP+cur]
// packed u32 (dlow<<16 | src). blockIdx-based rep => each cell written by
// blocks ≡ rep (mod 32) only => one XCD under %8 dispatch => L2-local writes.
// ---------------------------------------------------------------------------
__global__ __launch_bounds__(256) void binscatter_k(const int* __restrict__ src,
                                                    const int* __restrict__ dst,
                                                    int* __restrict__ bincur,
                                                    unsigned* __restrict__ tmp,
                                                    const float* __restrict__ W1,
                                                    const float* __restrict__ W2,
                                                    unsigned short* __restrict__ W1t,
                                                    unsigned short* __restrict__ W2t) {
    int e = blockIdx.x * blockDim.x + threadIdx.x;
    if (e < IN_DIM * HD) {                 // W1 [256][128] -> W1t [128][256]
        int k = e >> 7, n = e & 127;
        W1t[n * IN_DIM + k] = f2bf(W1[e]);
    }
    if (e < 48 * HD) {                     // W2 [128][40] -> W2t [48][128]
        int n = e >> 7, k = e & 127;
        float v = (n < NC) ? W2[k * NC + n] : 0.f;
        W2t[e] = f2bf(v);
    }
    if (e >= N_EDGES) return;
    int v = dst[e];
    int b = v >> 6;
    int rep = blockIdx.x & (NREP - 1);     // XCD-confined cells (see RCAP note)
    int cell = b * NREP + rep;
    int cur = atomicAdd(&bincur[cell], 1);
    if (cur < RCAP)
        tmp[(size_t)cell * RCAP + cur] = ((unsigned)(v & 63) << 16) | (unsigned)src[e];
}

// ---------------------------------------------------------------------------
// binsort: one block (4 waves) per bin. Reads the bin's 32 ragged segments
// (wave wv owns s = wv, wv+NWAVE, ...), LDS hist over 64 nodes + wave scan ->
// compact csrp, packed rowp (start | deg<<32), bintot.
// ---------------------------------------------------------------------------
__global__ __launch_bounds__(256) void binsort_k(const unsigned* __restrict__ tmp,
                                                 const int* __restrict__ bincur,
                                                 unsigned* __restrict__ csrp,
                                                 u64* __restrict__ rowp,
                                                 int* __restrict__ bintot) {
    __shared__ int cnts[NREP];
    __shared__ int hist[64];
    __shared__ int cur[64];
    int b = blockIdx.x, tid = threadIdx.x;
    int nbase = b << 6;
    size_t cbase = (size_t)b * BCAP;
    int wv = tid >> 6, ln = tid & 63;
    if (tid < NREP) cnts[tid] = min(bincur[b * NREP + tid], RCAP);
    if (tid < 64) hist[tid] = 0;
    __syncthreads();
    // pass 1: histogram (stride = NWAVE waves!)
    for (int s = wv; s < NREP; s += NWAVE) {
        int c = cnts[s];
        const unsigned* seg = tmp + (size_t)(b * NREP + s) * RCAP;
        for (int t = ln; t < c; t += 64)
            atomicAdd(&hist[seg[t] >> 16], 1);
    }
    __syncthreads();
    if (tid < 64) {
        int h = hist[tid];
        int v = h;
        #pragma unroll
        for (int off = 1; off < 64; off <<= 1) {
            int t2 = __shfl_up(v, off);
            if (tid >= off) v += t2;
        }
        int excl = v - h;
        cur[tid] = excl;
        int node = nbase + tid;
        if (node < N_NODES)
            rowp[node] = ((u64)h << 32) | (unsigned)(cbase + excl);
        if (tid == 63) bintot[b] = v;
    }
    __syncthreads();
    // pass 2: scatter into compact bin region (stride = NWAVE)
    for (int s = wv; s < NREP; s += NWAVE) {
        int c = cnts[s];
        const unsigned* seg = tmp + (size_t)(b * NREP + s) * RCAP;
        for (int t = ln; t < c; t += 64) {
            unsigned p = seg[t];
            int pos = atomicAdd(&cur[p >> 16], 1);
            csrp[cbase + pos] = p;
        }
    }
}

// ---------------------------------------------------------------------------
// MFMA GEMM1: ft1b = bf16( bf16(x) @ bf16(W1) ).  M=50000, K=256, N=128.
// ---------------------------------------------------------------------------
__global__ __launch_bounds__(256) void mfma1_k(const float* __restrict__ X,
                                               const unsigned short* __restrict__ W1t,
                                               unsigned short* __restrict__ ftb) {
    __shared__ unsigned short alds[2][64 * 32];
    __shared__ unsigned short wlds[2][128 * 32];
    const int tid = threadIdx.x;
    const int lane = tid & 63, wid = tid >> 6;
    const int wr = wid >> 1, wc = wid & 1;
    const int rowBase = blockIdx.x * 64;
    const int s_arow = tid >> 2, s_ac = tid & 3;
    const int s_wcol = tid >> 1, s_wc0 = (tid & 1) * 2;

    auto stageA = [&](int buf, int ks) {
        float4 v0 = make_float4(0.f,0.f,0.f,0.f), v1 = v0;
        int gr = rowBase + s_arow;
        if (gr < N_NODES) {
            const float4* p = (const float4*)(X + (size_t)gr * IN_DIM + ks * 32 + s_ac * 8);
            v0 = p[0]; v1 = p[1];
        }
        *(uint4*)&alds[buf][tile32_addr(s_arow, s_ac)] =
            pack8(v0.x,v0.y,v0.z,v0.w,v1.x,v1.y,v1.z,v1.w);
    };
    auto stageW = [&](int buf, int ks) {
        const uint4* g = (const uint4*)(W1t + s_wcol * IN_DIM + ks * 32 + s_wc0 * 8);
        uint4 a = g[0], b = g[1];
        *(uint4*)&wlds[buf][tile32_addr(s_wcol, s_wc0)] = a;
        *(uint4*)&wlds[buf][tile32_addr(s_wcol, s_wc0 + 1)] = b;
    };

    f32x4 acc[2][4];
    #pragma unroll
    for (int mf = 0; mf < 2; ++mf)
        #pragma unroll
        for (int nf = 0; nf < 4; ++nf)
            acc[mf][nf] = (f32x4){0.f, 0.f, 0.f, 0.f};

    stageA(0, 0); stageW(0, 0);
    for (int ks = 0; ks < 8; ++ks) {
        __syncthreads();
        if (ks < 7) { stageA((ks + 1) & 1, ks + 1); stageW((ks + 1) & 1, ks + 1); }
        int buf = ks & 1;
        bf16x8 afrag[2], bfrag[4];
        #pragma unroll
        for (int mf = 0; mf < 2; ++mf) {
            int row = wr * 32 + mf * 16 + (lane & 15);
            afrag[mf] = *(const bf16x8*)&alds[buf][tile32_addr(row, lane >> 4)];
        }
        #pragma unroll
        for (int nf = 0; nf < 4; ++nf) {
            int col = wc * 64 + nf * 16 + (lane & 15);
            bfrag[nf] = *(const bf16x8*)&wlds[buf][tile32_addr(col, lane >> 4)];
        }
        #pragma unroll
        for (int mf = 0; mf < 2; ++mf)
            #pragma unroll
            for (int nf = 0; nf < 4; ++nf)
                acc[mf][nf] = __builtin_amdgcn_mfma_f32_16x16x32_bf16(
                    afrag[mf], bfrag[nf], acc[mf][nf], 0, 0, 0);
    }
    #pragma unroll
    for (int mf = 0; mf < 2; ++mf) {
        int r0 = rowBase + wr * 32 + mf * 16 + (lane >> 4) * 4;
        #pragma unroll
        for (int nf = 0; nf < 4; ++nf) {
            int col = wc * 64 + nf * 16 + (lane & 15);
            #pragma unroll
            for (int v = 0; v < 4; ++v) {
                int r = r0 + v;
                if (r < N_NODES) ftb[(size_t)r * HD + col] = f2bf(acc[mf][nf][v]);
            }
        }
    }
}

// ---------------------------------------------------------------------------
// MFMA GEMM2: ft2b = bf16( elu(bn(h1b)) @ W2 ). BN fold in prologue.
// ---------------------------------------------------------------------------
__global__ __launch_bounds__(256) void mfma2_k(const unsigned short* __restrict__ Hin,
                                               const unsigned short* __restrict__ W2t,
                                               const float* __restrict__ bnsum,
                                               const float* __restrict__ bnsq,
                                               const float* __restrict__ gamma,
                                               const float* __restrict__ beta,
                                               unsigned short* __restrict__ ft2b) {
    __shared__ unsigned short alds[2][64 * 32];
    __shared__ unsigned short wlds[48 * 128];
    __shared__ float sc_lds[HD], sh_lds[HD];
    const int tid = threadIdx.x;
    const int lane = tid & 63, wid = tid >> 6;
    const int rowBase = blockIdx.x * 64;
    const int s_arow = tid >> 2, s_ac = tid & 3;

    if (tid < HD) {
        const float invN = 1.0f / (float)N_NODES;
        float mu = bnsum[tid] * invN;
        float var = bnsq[tid] * invN - mu * mu;
        float sc = gamma[tid] * rsqrtf(var + EPS_BN);
        sc_lds[tid] = sc;
        sh_lds[tid] = beta[tid] - mu * sc;
    }
    for (int i = tid; i < 48 * 16; i += 256) {
        int col = i >> 4, c = i & 15;
        uint4 v = *(const uint4*)(W2t + col * HD + c * 8);
        *(uint4*)&wlds[col * HD + ((c ^ (col & 7)) << 3)] = v;
    }
    __syncthreads();

    auto stageA = [&](int buf, int ks) {
        int c0 = ks * 32 + s_ac * 8;
        uint4 pv = make_uint4(0,0,0,0);
        int gr = rowBase + s_arow;
        if (gr < N_NODES) pv = *(const uint4*)(Hin + (size_t)gr * HD + c0);
        float4 sc0 = *(const float4*)(sc_lds + c0), sc1 = *(const float4*)(sc_lds + c0 + 4);
        float4 sh0 = *(const float4*)(sh_lds + c0), sh1 = *(const float4*)(sh_lds + c0 + 4);
        float t[8];
        t[0] = fmaf(bf2f(pv.x & 0xffff), sc0.x, sh0.x);
        t[1] = fmaf(bf2f(pv.x >> 16),    sc0.y, sh0.y);
        t[2] = fmaf(bf2f(pv.y & 0xffff), sc0.z, sh0.z);
        t[3] = fmaf(bf2f(pv.y >> 16),    sc0.w, sh0.w);
        t[4] = fmaf(bf2f(pv.z & 0xffff), sc1.x, sh1.x);
        t[5] = fmaf(bf2f(pv.z >> 16),    sc1.y, sh1.y);
        t[6] = fmaf(bf2f(pv.w & 0xffff), sc1.z, sh1.z);
        t[7] = fmaf(bf2f(pv.w >> 16),    sc1.w, sh1.w);
        #pragma unroll
        for (int i = 0; i < 8; ++i) t[i] = t[i] > 0.f ? t[i] : expm1f(t[i]);
        *(uint4*)&alds[buf][tile32_addr(s_arow, s_ac)] =
            pack8(t[0],t[1],t[2],t[3],t[4],t[5],t[6],t[7]);
    };

    f32x4 acc[3];
    #pragma unroll
    for (int nf = 0; nf < 3; ++nf) acc[nf] = (f32x4){0.f, 0.f, 0.f, 0.f};

    stageA(0, 0);
    for (int ks = 0; ks < 4; ++ks) {
        __syncthreads();
        if (ks < 3) stageA((ks + 1) & 1, ks + 1);
        int buf = ks & 1;
        int row = wid * 16 + (lane & 15);
        bf16x8 a = *(const bf16x8*)&alds[buf][tile32_addr(row, lane >> 4)];
        #pragma unroll
        for (int nf = 0; nf < 3; ++nf) {
            int col = nf * 16 + (lane & 15);
            int c = ks * 4 + (lane >> 4);
            bf16x8 b = *(const bf16x8*)&wlds[col * HD + ((c ^ (col & 7)) << 3)];
            acc[nf] = __builtin_amdgcn_mfma_f32_16x16x32_bf16(a, b, acc[nf], 0, 0, 0);
        }
    }
    int r0 = rowBase + wid * 16 + (lane >> 4) * 4;
    #pragma unroll
    for (int nf = 0; nf < 3; ++nf) {
        int col = nf * 16 + (lane & 15);
        if (col < NC) {
            #pragma unroll
            for (int v = 0; v < 4; ++v) {
                int r = r0 + v;
                if (r < N_NODES) ft2b[(size_t)r * NC + col] = f2bf(acc[nf][v]);
            }
        }
    }
}

// ---------------------------------------------------------------------------
// el/er layer 1 from bf16 features
// ---------------------------------------------------------------------------
__global__ void eler1b_k(const unsigned short* __restrict__ ftb,
                         const float* __restrict__ alw, const float* __restrict__ arw,
                         float* __restrict__ el, float* __restrict__ er) {
    int t = blockIdx.x * blockDim.x + threadIdx.x;
    if (t >= N_NODES * H1) return;
    int n = t >> 2, h = t & 3;
    const unsigned short* f = ftb + (size_t)n * HD + h * D;
    const float* a = alw + h * D;
    const float* r = arw + h * D;
    float sl = 0.f, sr = 0.f;
    #pragma unroll
    for (int d = 0; d < D; d += 8) {
        uint4 fv = *(const uint4*)(f + d);
        float x0 = bf2f(fv.x & 0xffff), x1 = bf2f(fv.x >> 16);
        float x2 = bf2f(fv.y & 0xffff), x3 = bf2f(fv.y >> 16);
        float x4 = bf2f(fv.z & 0xffff), x5 = bf2f(fv.z >> 16);
        float x6 = bf2f(fv.w & 0xffff), x7 = bf2f(fv.w >> 16);
        sl += x0*a[d] + x1*a[d+1] + x2*a[d+2] + x3*a[d+3]
            + x4*a[d+4] + x5*a[d+5] + x6*a[d+6] + x7*a[d+7];
        sr += x0*r[d] + x1*r[d+1] + x2*r[d+2] + x3*r[d+3]
            + x4*r[d+4] + x5*r[d+5] + x6*r[d+6] + x7*r[d+7];
    }
    el[t] = sl; er[t] = sr;
}

// el/er for layer 2 from bf16 ft2
__global__ void eler2b_k(const unsigned short* __restrict__ ft2b,
                         const float* __restrict__ alw, const float* __restrict__ arw,
                         float* __restrict__ el, float* __restrict__ er) {
    int n = blockIdx.x * blockDim.x + threadIdx.x;
    if (n >= N_NODES) return;
    const unsigned short* f = ft2b + (size_t)n * NC;
    float sl = 0.f, sr = 0.f;
    #pragma unroll
    for (int d = 0; d < NC; d += 4) {
        uint2 fv = *(const uint2*)(f + d);
        float x0 = bf2f(fv.x & 0xffff), x1 = bf2f(fv.x >> 16);
        float x2 = bf2f(fv.y & 0xffff), x3 = bf2f(fv.y >> 16);
        sl += x0*alw[d] + x1*alw[d+1] + x2*alw[d+2] + x3*alw[d+3];
        sr += x0*arw[d] + x1*arw[d+1] + x2*arw[d+2] + x3*arw[d+3];
    }
    el[n] = sl; er[n] = sr;
}

// ---------------------------------------------------------------------------
// layer-2 edge weights (one exp per edge, coalesced) over bin-slot space
// ---------------------------------------------------------------------------
__global__ void exw2_k(const unsigned* __restrict__ csrp,
                       const int* __restrict__ bintot,
                       const float* __restrict__ el, const float* __restrict__ er,
                       float* __restrict__ exw) {
    int s = blockIdx.x * blockDim.x + threadIdx.x;
    int b = s / BCAP;
    int off = s - b * BCAP;
    if (off >= bintot[b]) return;
    unsigned p = csrp[s];
    float t = el[p & 0xffff] + er[(b << 6) + (p >> 16)];
    t = t > 0.f ? t : SLOPE * t;
    exw[s] = __expf(t);
}

// ---------------------------------------------------------------------------
// layer-1 gather, fused attention weights: one wave per dst node; lane owns
// bf16x2 of 128 dims, head hh = lane>>4. Unroll 8. Writes bf16 h1.
// ---------------------------------------------------------------------------
__global__ __launch_bounds__(256) void gather1_k(const u64* __restrict__ rowp,
                                                 const unsigned* __restrict__ csrp,
                                                 const float* __restrict__ el,
                                                 const float* __restrict__ er,
                                                 const unsigned short* __restrict__ ftb,
                                                 unsigned int* __restrict__ h1b) {
    int w = (blockIdx.x * blockDim.x + threadIdx.x) >> 6;   // node
    if (w >= N_NODES) return;
    int lane = threadIdx.x & 63;
    int hh = lane >> 4;
    float erv = er[w * H1 + hh];
    u64 rp = rowp[w];
    int jb = (int)(rp & 0xffffffffu), je = jb + (int)(rp >> 32);
    float ax = 0.f, ay = 0.f, ssum = 0.f;
    int j = jb;
    for (; j + 7 < je; j += 8) {
        int u[8]; float wv[8]; ushort2 f[8];
        #pragma unroll
        for (int k = 0; k < 8; ++k) u[k] = csrp[j + k] & 0xffff;
        #pragma unroll
        for (int k = 0; k < 8; ++k)
            f[k] = *(const ushort2*)(ftb + (size_t)u[k] * HD + lane * 2);
        #pragma unroll
        for (int k = 0; k < 8; ++k) {
            float t = el[u[k] * H1 + hh] + erv;
            t = t > 0.f ? t : SLOPE * t;
            wv[k] = __expf(t);
        }
        #pragma unroll
        for (int k = 0; k < 8; ++k) {
            ax = fmaf(wv[k], bf2f(f[k].x), ax);
            ay = fmaf(wv[k], bf2f(f[k].y), ay);
            ssum += wv[k];
        }
    }
    for (; j < je; ++j) {
        int u0 = csrp[j] & 0xffff;
        float t = el[u0 * H1 + hh] + erv;
        t = t > 0.f ? t : SLOPE * t;
        float w0 = __expf(t);
        ushort2 f0 = *(const ushort2*)(ftb + (size_t)u0 * HD + lane * 2);
        ax = fmaf(w0, bf2f(f0.x), ax); ay = fmaf(w0, bf2f(f0.y), ay);
        ssum += w0;
    }
    float inv = 1.0f / fmaxf(ssum, 1e-9f);
    h1b[(size_t)w * 64 + lane] = (unsigned)f2bf(ax * inv)
                               | ((unsigned)f2bf(ay * inv) << 16);
}

// ---------------------------------------------------------------------------
// BN stats on bf16 h1
// ---------------------------------------------------------------------------
__global__ void bnstats_k(const unsigned short* __restrict__ h1b,
                          float* __restrict__ sums, float* __restrict__ sumsq) {
    int c = threadIdx.x;  // 128 threads
    float acc = 0.f, acc2 = 0.f;
    for (int r = blockIdx.x; r < N_NODES; r += gridDim.x) {
        float v = bf2f(h1b[(size_t)r * HD + c]);
        acc += v; acc2 += v * v;
    }
    atomicAdd(&sums[c], acc);
    atomicAdd(&sumsq[c], acc2);
}

// ---------------------------------------------------------------------------
// layer-2 gather (precomputed exw) fused with log_softmax. Unroll 8.
// ---------------------------------------------------------------------------
__global__ __launch_bounds__(256) void gather2_k(const u64* __restrict__ rowp,
                                                 const unsigned* __restrict__ csrp,
                                                 const float* __restrict__ exw,
                                                 const unsigned short* __restrict__ ft2b,
                                                 float* __restrict__ out) {
    int w = (blockIdx.x * blockDim.x + threadIdx.x) >> 6;   // node
    if (w >= N_NODES) return;
    int lane = threadIdx.x & 63;
    u64 rp = rowp[w];
    int jb = (int)(rp & 0xffffffffu), je = jb + (int)(rp >> 32);
    float acc = 0.f, ssum = 0.f;
    int j = jb;
    for (; j + 7 < je; j += 8) {
        int u[8]; float wv[8]; float fv[8];
        #pragma unroll
        for (int k = 0; k < 8; ++k) u[k] = csrp[j + k] & 0xffff;
        #pragma unroll
        for (int k = 0; k < 8; ++k)
            fv[k] = (lane < NC) ? bf2f(ft2b[(size_t)u[k] * NC + lane]) : 0.f;
        #pragma unroll
        for (int k = 0; k < 8; ++k) wv[k] = exw[j + k];
        #pragma unroll
        for (int k = 0; k < 8; ++k) {
            acc = fmaf(wv[k], fv[k], acc);
            ssum += wv[k];
        }
    }
    for (; j < je; ++j) {
        int u0 = csrp[j] & 0xffff;
        float w0 = exw[j];
        float fa = (lane < NC) ? bf2f(ft2b[(size_t)u0 * NC + lane]) : 0.f;
        acc = fmaf(w0, fa, acc);
        ssum += w0;
    }
    float v = acc / fmaxf(ssum, 1e-9f);
    float vv = (lane < NC) ? v : -INFINITY;
    float m = vv;
    #pragma unroll
    for (int off = 32; off; off >>= 1) m = fmaxf(m, __shfl_xor(m, off));
    float ex2 = (lane < NC) ? __expf(vv - m) : 0.f;
    float sum = ex2;
    #pragma unroll
    for (int off = 32; off; off >>= 1) sum += __shfl_xor(sum, off);
    if (lane < NC) out[(size_t)w * NC + lane] = vv - m - logf(sum);
}

// ---------------------------------------------------------------------------
extern "C" void kernel_launch(void* const* d_in, const int* in_sizes, int n_in,
                              void* d_out, int out_size, void* d_ws, size_t ws_size,
                              hipStream_t stream) {
    const float* x     = (const float*)d_in[0];
    const int*   src   = (const int*)  d_in[1];
    const int*   dst   = (const int*)  d_in[2];
    const float* W1    = (const float*)d_in[3];
    const float* al1   = (const float*)d_in[4];
    const float* ar1   = (const float*)d_in[5];
    const float* gamma = (const float*)d_in[6];
    const float* beta  = (const float*)d_in[7];
    const float* W2    = (const float*)d_in[8];
    const float* al2   = (const float*)d_in[9];
    const float* ar2   = (const float*)d_in[10];
    float* out = (float*)d_out;

    const size_t NSLOT = (size_t)NBIN * BCAP;          // 1,201,152 compact slots
    const size_t NTMP  = (size_t)NBIN * NREP * RCAP;   // 4,003,840 tmp slots

    char* ws = (char*)d_ws;
    size_t o = 0;
    auto allocB = [&](size_t bytes) { void* p = ws + o; o += (bytes + 15) & ~15ull; return p; };
    // ---- zeroed region (one ~100KB memset) ----
    int*   bincur = (int*)allocB((size_t)NBIN * NREP * 4);
    float* bnsum  = (float*)allocB(HD * 4);
    float* bnsq   = (float*)allocB(HD * 4);
    size_t zeroBytes = o;
    // ---- uninitialized region ----
    unsigned* tmp  = (unsigned*)allocB(NTMP * 4);
    unsigned* csrp = (unsigned*)allocB(NSLOT * 4);
    int*   bintot  = (int*)allocB(NBIN * 4);
    u64*   rowp    = (u64*)allocB((size_t)N_NODES * 8);
    float* exw2    = (float*)allocB(NSLOT * 4);
    unsigned short* w1t  = (unsigned short*)allocB((size_t)IN_DIM * HD * 2);
    unsigned short* w2t  = (unsigned short*)allocB((size_t)48 * HD * 2);
    unsigned short* ft1b = (unsigned short*)allocB((size_t)N_NODES * HD * 2);
    unsigned int*   h1b  = (unsigned int*)allocB((size_t)N_NODES * HD * 2);
    float* el1  = (float*)allocB(N_NODES * H1 * 4);
    float* er1  = (float*)allocB(N_NODES * H1 * 4);
    unsigned short* ft2b = (unsigned short*)allocB((size_t)N_NODES * NC * 2);
    float* el2  = (float*)allocB(N_NODES * 4);
    float* er2  = (float*)allocB(N_NODES * 4);

    hipMemsetAsync(d_ws, 0, zeroBytes, stream);

    const int NB_E = (N_EDGES + 255) / 256;            // 3321
    const int NB_G = (N_NODES + 63) / 64;              // 782
    const int NB_S = (int)(NSLOT / 256);               // 4692 (BCAP%256==0)

    // CSR build (binned, XCD-confined cursor cells) + weight cvt
    binscatter_k<<<NB_E, 256, 0, stream>>>(src, dst, bincur, tmp, W1, W2, w1t, w2t);
    binsort_k<<<NBIN, 256, 0, stream>>>(tmp, bincur, csrp, rowp, bintot);

    // layer 1
    mfma1_k<<<NB_G, 256, 0, stream>>>(x, w1t, ft1b);
    eler1b_k<<<(N_NODES * H1 + 255) / 256, 256, 0, stream>>>(ft1b, al1, ar1, el1, er1);
    gather1_k<<<N_NODES / 4, 256, 0, stream>>>(rowp, csrp, el1, er1, ft1b, h1b);

    bnstats_k<<<512, HD, 0, stream>>>((const unsigned short*)h1b, bnsum, bnsq);

    // layer 2 (BN fold + ELU fused into GEMM2 A-staging)
    mfma2_k<<<NB_G, 256, 0, stream>>>((const unsigned short*)h1b, w2t,
                                      bnsum, bnsq, gamma, beta, ft2b);
    eler2b_k<<<(N_NODES + 255) / 256, 256, 0, stream>>>(ft2b, al2, ar2, el2, er2);
    exw2_k<<<NB_S, 256, 0, stream>>>(csrp, bintot, el2, er2, exw2);
    gather2_k<<<N_NODES / 4, 256, 0, stream>>>(rowp, csrp, exw2, ft2b, out);
}

// Round 12
// 328.517 us; speedup vs baseline: 1.0912x; 1.0912x over previous
//
#include <hip/hip_runtime.h>
#include <hip/hip_bf16.h>
#include <math.h>

#define N_NODES 50000
#define N_EDGES 850000
#define IN_DIM  256
#define HD      128      // H1*D
#define H1      4
#define D       32
#define NC      40       // num classes
#define SLOPE   0.2f
#define EPS_BN  1e-5f

#define NBIN    782      // ceil(50000/64) destination bins of 64 nodes
#define BCAP    1536     // compact slots per bin (mean 1088, sigma ~33)
#define NREP    32       // cursor replicas per bin
#define RCAP    160      // slots/(bin,rep): block-based rep -> loop cells ~96 mean
#define NWAVE   4        // waves per 256-thread block (binsort strides by THIS)
#define NB_G    782      // mfma1 tile blocks
#define NB_E    3321     // binscatter blocks ((850000+255)/256)

typedef __attribute__((ext_vector_type(8))) short bf16x8;
typedef __attribute__((ext_vector_type(4))) float f32x4;
typedef unsigned long long u64;

__device__ __forceinline__ unsigned short f2bf(float x) {
    union { float f; unsigned u; } v; v.f = x;
    unsigned r = v.u + 0x7FFF + ((v.u >> 16) & 1);   // RNE
    return (unsigned short)(r >> 16);
}
__device__ __forceinline__ float bf2f(unsigned short h) {
    union { unsigned u; float f; } v; v.u = ((unsigned)h) << 16;
    return v.f;
}
__device__ __forceinline__ uint4 pack8(float a0,float a1,float a2,float a3,
                                       float a4,float a5,float a6,float a7) {
    uint4 p;
    p.x = f2bf(a0) | ((unsigned)f2bf(a1) << 16);
    p.y = f2bf(a2) | ((unsigned)f2bf(a3) << 16);
    p.z = f2bf(a4) | ((unsigned)f2bf(a5) << 16);
    p.w = f2bf(a6) | ((unsigned)f2bf(a7) << 16);
    return p;
}

// chunk-swizzled [rows][32] bf16 tile: 4 chunks of 8 bf16 per row (64B rows).
__device__ __forceinline__ int tile32_addr(int row, int chunk) {
    return row * 32 + ((chunk ^ ((row >> 1) & 3)) << 3);
}

// ---------------------------------------------------------------------------
// cvtw0: weight cvt/transpose + zero bincur/bnsum/bnsq (replaces memset)
// ---------------------------------------------------------------------------
__global__ void cvtw0_k(const float* __restrict__ W1, const float* __restrict__ W2,
                        unsigned short* __restrict__ W1t, unsigned short* __restrict__ W2t,
                        int* __restrict__ bincur, float* __restrict__ bnsum,
                        float* __restrict__ bnsq) {
    int id = blockIdx.x * blockDim.x + threadIdx.x;
    if (id < IN_DIM * HD) {                 // W1 [256][128] -> W1t [128][256]
        int k = id >> 7, n = id & 127;
        W1t[n * IN_DIM + k] = f2bf(W1[id]);
    }
    if (id < 48 * HD) {                     // W2 [128][40] -> W2t [48][128]
        int n = id >> 7, k = id & 127;
        float v = (n < NC) ? W2[k * NC + n] : 0.f;
        W2t[id] = f2bf(v);
    }
    if (id < NBIN * NREP) bincur[id] = 0;
    if (id < HD) { bnsum[id] = 0.f; bnsq[id] = 0.f; }
}

// ---------------------------------------------------------------------------
// Fused A: blocks [0,NB_G) = MFMA GEMM1 + el1/er1 epilogue;
//          blocks [NB_G, NB_G+NB_E) = binscatter.
// Independent work co-resident on CUs: binscatter's atomic-latency stalls are
// hidden under GEMM compute.
// ---------------------------------------------------------------------------
__global__ __launch_bounds__(256) void fusedA_k(const float* __restrict__ X,
                                                const unsigned short* __restrict__ W1t,
                                                const float* __restrict__ al1,
                                                const float* __restrict__ ar1,
                                                unsigned short* __restrict__ ftb,
                                                float* __restrict__ el,
                                                float* __restrict__ er,
                                                const int* __restrict__ src,
                                                const int* __restrict__ dst,
                                                int* __restrict__ bincur,
                                                unsigned* __restrict__ tmp) {
    __shared__ unsigned short alds[2][64 * 32];
    __shared__ unsigned short wlds[2][128 * 32];

    if (blockIdx.x >= NB_G) {
        // ---------------- binscatter path ----------------
        int bb = blockIdx.x - NB_G;
        int e = bb * 256 + threadIdx.x;
        if (e >= N_EDGES) return;
        int v = dst[e];
        int b = v >> 6;
        int rep = bb & (NREP - 1);          // block-based: cell confined to one XCD
        int cell = b * NREP + rep;
        int cur = atomicAdd(&bincur[cell], 1);
        if (cur < RCAP)
            tmp[(size_t)cell * RCAP + cur] = ((unsigned)(v & 63) << 16) | (unsigned)src[e];
        return;
    }

    // ---------------- mfma1 path ----------------
    const int tid = threadIdx.x;
    const int lane = tid & 63, wid = tid >> 6;
    const int wr = wid >> 1, wc = wid & 1;
    const int rowBase = blockIdx.x * 64;
    const int s_arow = tid >> 2, s_ac = tid & 3;
    const int s_wcol = tid >> 1, s_wc0 = (tid & 1) * 2;

    auto stageA = [&](int buf, int ks) {
        float4 v0 = make_float4(0.f,0.f,0.f,0.f), v1 = v0;
        int gr = rowBase + s_arow;
        if (gr < N_NODES) {
            const float4* p = (const float4*)(X + (size_t)gr * IN_DIM + ks * 32 + s_ac * 8);
            v0 = p[0]; v1 = p[1];
        }
        *(uint4*)&alds[buf][tile32_addr(s_arow, s_ac)] =
            pack8(v0.x,v0.y,v0.z,v0.w,v1.x,v1.y,v1.z,v1.w);
    };
    auto stageW = [&](int buf, int ks) {
        const uint4* g = (const uint4*)(W1t + s_wcol * IN_DIM + ks * 32 + s_wc0 * 8);
        uint4 a = g[0], b = g[1];
        *(uint4*)&wlds[buf][tile32_addr(s_wcol, s_wc0)] = a;
        *(uint4*)&wlds[buf][tile32_addr(s_wcol, s_wc0 + 1)] = b;
    };

    f32x4 acc[2][4];
    #pragma unroll
    for (int mf = 0; mf < 2; ++mf)
        #pragma unroll
        for (int nf = 0; nf < 4; ++nf)
            acc[mf][nf] = (f32x4){0.f, 0.f, 0.f, 0.f};

    stageA(0, 0); stageW(0, 0);
    for (int ks = 0; ks < 8; ++ks) {
        __syncthreads();
        if (ks < 7) { stageA((ks + 1) & 1, ks + 1); stageW((ks + 1) & 1, ks + 1); }
        int buf = ks & 1;
        bf16x8 afrag[2], bfrag[4];
        #pragma unroll
        for (int mf = 0; mf < 2; ++mf) {
            int row = wr * 32 + mf * 16 + (lane & 15);
            afrag[mf] = *(const bf16x8*)&alds[buf][tile32_addr(row, lane >> 4)];
        }
        #pragma unroll
        for (int nf = 0; nf < 4; ++nf) {
            int col = wc * 64 + nf * 16 + (lane & 15);
            bfrag[nf] = *(const bf16x8*)&wlds[buf][tile32_addr(col, lane >> 4)];
        }
        #pragma unroll
        for (int mf = 0; mf < 2; ++mf)
            #pragma unroll
            for (int nf = 0; nf < 4; ++nf)
                acc[mf][nf] = __builtin_amdgcn_mfma_f32_16x16x32_bf16(
                    afrag[mf], bfrag[nf], acc[mf][nf], 0, 0, 0);
    }
    // C write (bf16)
    #pragma unroll
    for (int mf = 0; mf < 2; ++mf) {
        int r0 = rowBase + wr * 32 + mf * 16 + (lane >> 4) * 4;
        #pragma unroll
        for (int nf = 0; nf < 4; ++nf) {
            int col = wc * 64 + nf * 16 + (lane & 15);
            #pragma unroll
            for (int v = 0; v < 4; ++v) {
                int r = r0 + v;
                if (r < N_NODES) ftb[(size_t)r * HD + col] = f2bf(acc[mf][nf][v]);
            }
        }
    }
    // el/er epilogue: this wave's 64 cols = heads {wc*2, wc*2+1} complete.
    float alw[4], arw[4];
    #pragma unroll
    for (int nf = 0; nf < 4; ++nf) {
        int col = wc * 64 + nf * 16 + (lane & 15);
        alw[nf] = al1[(col >> 5) * D + (col & 31)];
        arw[nf] = ar1[(col >> 5) * D + (col & 31)];
    }
    #pragma unroll
    for (int mf = 0; mf < 2; ++mf) {
        #pragma unroll
        for (int v = 0; v < 4; ++v) {
            int r = rowBase + wr * 32 + mf * 16 + (lane >> 4) * 4 + v;
            float elA = acc[mf][0][v] * alw[0] + acc[mf][1][v] * alw[1];
            float erA = acc[mf][0][v] * arw[0] + acc[mf][1][v] * arw[1];
            float elB = acc[mf][2][v] * alw[2] + acc[mf][3][v] * alw[3];
            float erB = acc[mf][2][v] * arw[2] + acc[mf][3][v] * arw[3];
            #pragma unroll
            for (int off = 1; off < 16; off <<= 1) {
                elA += __shfl_xor(elA, off, 16);
                erA += __shfl_xor(erA, off, 16);
                elB += __shfl_xor(elB, off, 16);
                erB += __shfl_xor(erB, off, 16);
            }
            if ((lane & 15) == 0 && r < N_NODES) {
                int hA = wc * 2;
                el[r * H1 + hA]     = elA;  er[r * H1 + hA]     = erA;
                el[r * H1 + hA + 1] = elB;  er[r * H1 + hA + 1] = erB;
            }
        }
    }
}

// ---------------------------------------------------------------------------
// binsort: one block (4 waves) per bin -> compact csrp, rowp, bintot.
// ---------------------------------------------------------------------------
__global__ __launch_bounds__(256) void binsort_k(const unsigned* __restrict__ tmp,
                                                 const int* __restrict__ bincur,
                                                 unsigned* __restrict__ csrp,
                                                 u64* __restrict__ rowp,
                                                 int* __restrict__ bintot) {
    __shared__ int cnts[NREP];
    __shared__ int hist[64];
    __shared__ int cur[64];
    int b = blockIdx.x, tid = threadIdx.x;
    int nbase = b << 6;
    size_t cbase = (size_t)b * BCAP;
    int wv = tid >> 6, ln = tid & 63;
    if (tid < NREP) cnts[tid] = min(bincur[b * NREP + tid], RCAP);
    if (tid < 64) hist[tid] = 0;
    __syncthreads();
    for (int s = wv; s < NREP; s += NWAVE) {
        int c = cnts[s];
        const unsigned* seg = tmp + (size_t)(b * NREP + s) * RCAP;
        for (int t = ln; t < c; t += 64)
            atomicAdd(&hist[seg[t] >> 16], 1);
    }
    __syncthreads();
    if (tid < 64) {
        int h = hist[tid];
        int v = h;
        #pragma unroll
        for (int off = 1; off < 64; off <<= 1) {
            int t2 = __shfl_up(v, off);
            if (tid >= off) v += t2;
        }
        int excl = v - h;
        cur[tid] = excl;
        int node = nbase + tid;
        if (node < N_NODES)
            rowp[node] = ((u64)h << 32) | (unsigned)(cbase + excl);
        if (tid == 63) bintot[b] = v;
    }
    __syncthreads();
    for (int s = wv; s < NREP; s += NWAVE) {
        int c = cnts[s];
        const unsigned* seg = tmp + (size_t)(b * NREP + s) * RCAP;
        for (int t = ln; t < c; t += 64) {
            unsigned p = seg[t];
            int pos = atomicAdd(&cur[p >> 16], 1);
            csrp[cbase + pos] = p;
        }
    }
}

// ---------------------------------------------------------------------------
// MFMA GEMM2 + el2/er2 epilogue: ft2b = bf16( elu(bn(h1b)) @ W2 ).
// ---------------------------------------------------------------------------
__global__ __launch_bounds__(256) void mfma2_k(const unsigned short* __restrict__ Hin,
                                               const unsigned short* __restrict__ W2t,
                                               const float* __restrict__ bnsum,
                                               const float* __restrict__ bnsq,
                                               const float* __restrict__ gamma,
                                               const float* __restrict__ beta,
                                               const float* __restrict__ al2,
                                               const float* __restrict__ ar2,
                                               unsigned short* __restrict__ ft2b,
                                               float* __restrict__ el2,
                                               float* __restrict__ er2) {
    __shared__ unsigned short alds[2][64 * 32];
    __shared__ unsigned short wlds[48 * 128];
    __shared__ float sc_lds[HD], sh_lds[HD];
    const int tid = threadIdx.x;
    const int lane = tid & 63, wid = tid >> 6;
    const int rowBase = blockIdx.x * 64;
    const int s_arow = tid >> 2, s_ac = tid & 3;

    if (tid < HD) {
        const float invN = 1.0f / (float)N_NODES;
        float mu = bnsum[tid] * invN;
        float var = bnsq[tid] * invN - mu * mu;
        float sc = gamma[tid] * rsqrtf(var + EPS_BN);
        sc_lds[tid] = sc;
        sh_lds[tid] = beta[tid] - mu * sc;
    }
    for (int i = tid; i < 48 * 16; i += 256) {
        int col = i >> 4, c = i & 15;
        uint4 v = *(const uint4*)(W2t + col * HD + c * 8);
        *(uint4*)&wlds[col * HD + ((c ^ (col & 7)) << 3)] = v;
    }
    __syncthreads();

    auto stageA = [&](int buf, int ks) {
        int c0 = ks * 32 + s_ac * 8;
        uint4 pv = make_uint4(0,0,0,0);
        int gr = rowBase + s_arow;
        if (gr < N_NODES) pv = *(const uint4*)(Hin + (size_t)gr * HD + c0);
        float4 sc0 = *(const float4*)(sc_lds + c0), sc1 = *(const float4*)(sc_lds + c0 + 4);
        float4 sh0 = *(const float4*)(sh_lds + c0), sh1 = *(const float4*)(sh_lds + c0 + 4);
        float t[8];
        t[0] = fmaf(bf2f(pv.x & 0xffff), sc0.x, sh0.x);
        t[1] = fmaf(bf2f(pv.x >> 16),    sc0.y, sh0.y);
        t[2] = fmaf(bf2f(pv.y & 0xffff), sc0.z, sh0.z);
        t[3] = fmaf(bf2f(pv.y >> 16),    sc0.w, sh0.w);
        t[4] = fmaf(bf2f(pv.z & 0xffff), sc1.x, sh1.x);
        t[5] = fmaf(bf2f(pv.z >> 16),    sc1.y, sh1.y);
        t[6] = fmaf(bf2f(pv.w & 0xffff), sc1.z, sh1.z);
        t[7] = fmaf(bf2f(pv.w >> 16),    sc1.w, sh1.w);
        #pragma unroll
        for (int i = 0; i < 8; ++i) t[i] = t[i] > 0.f ? t[i] : expm1f(t[i]);
        *(uint4*)&alds[buf][tile32_addr(s_arow, s_ac)] =
            pack8(t[0],t[1],t[2],t[3],t[4],t[5],t[6],t[7]);
    };

    f32x4 acc[3];
    #pragma unroll
    for (int nf = 0; nf < 3; ++nf) acc[nf] = (f32x4){0.f, 0.f, 0.f, 0.f};

    stageA(0, 0);
    for (int ks = 0; ks < 4; ++ks) {
        __syncthreads();
        if (ks < 3) stageA((ks + 1) & 1, ks + 1);
        int buf = ks & 1;
        int row = wid * 16 + (lane & 15);
        bf16x8 a = *(const bf16x8*)&alds[buf][tile32_addr(row, lane >> 4)];
        #pragma unroll
        for (int nf = 0; nf < 3; ++nf) {
            int col = nf * 16 + (lane & 15);
            int c = ks * 4 + (lane >> 4);
            bf16x8 b = *(const bf16x8*)&wlds[col * HD + ((c ^ (col & 7)) << 3)];
            acc[nf] = __builtin_amdgcn_mfma_f32_16x16x32_bf16(a, b, acc[nf], 0, 0, 0);
        }
    }
    int r0 = rowBase + wid * 16 + (lane >> 4) * 4;
    #pragma unroll
    for (int nf = 0; nf < 3; ++nf) {
        int col = nf * 16 + (lane & 15);
        if (col < NC) {
            #pragma unroll
            for (int v = 0; v < 4; ++v) {
                int r = r0 + v;
                if (r < N_NODES) ft2b[(size_t)r * NC + col] = f2bf(acc[nf][v]);
            }
        }
    }
    // el2/er2 epilogue: wave holds all 40 (padded 48) cols of its 16 rows.
    float alw2[3], arw2[3];
    #pragma unroll
    for (int nf = 0; nf < 3; ++nf) {
        int col = nf * 16 + (lane & 15);
        alw2[nf] = (col < NC) ? al2[col] : 0.f;
        arw2[nf] = (col < NC) ? ar2[col] : 0.f;
    }
    #pragma unroll
    for (int v = 0; v < 4; ++v) {
        int r = r0 + v;
        float e_l = acc[0][v] * alw2[0] + acc[1][v] * alw2[1] + acc[2][v] * alw2[2];
        float e_r = acc[0][v] * arw2[0] + acc[1][v] * arw2[1] + acc[2][v] * arw2[2];
        #pragma unroll
        for (int off = 1; off < 16; off <<= 1) {
            e_l += __shfl_xor(e_l, off, 16);
            e_r += __shfl_xor(e_r, off, 16);
        }
        if ((lane & 15) == 0 && r < N_NODES) { el2[r] = e_l; er2[r] = e_r; }
    }
}

// ---------------------------------------------------------------------------
// layer-2 edge weights (one exp per edge, coalesced) over bin-slot space
// ---------------------------------------------------------------------------
__global__ void exw2_k(const unsigned* __restrict__ csrp,
                       const int* __restrict__ bintot,
                       const float* __restrict__ el, const float* __restrict__ er,
                       float* __restrict__ exw) {
    int s = blockIdx.x * blockDim.x + threadIdx.x;
    int b = s / BCAP;
    int off = s - b * BCAP;
    if (off >= bintot[b]) return;
    unsigned p = csrp[s];
    float t = el[p & 0xffff] + er[(b << 6) + (p >> 16)];
    t = t > 0.f ? t : SLOPE * t;
    exw[s] = __expf(t);
}

// ---------------------------------------------------------------------------
// layer-1 gather, fused attention weights: one wave per dst node; lane owns
// bf16x2 of 128 dims, head hh = lane>>4. Unroll 8. Writes bf16 h1.
// ---------------------------------------------------------------------------
__global__ __launch_bounds__(256) void gather1_k(const u64* __restrict__ rowp,
                                                 const unsigned* __restrict__ csrp,
                                                 const float* __restrict__ el,
                                                 const float* __restrict__ er,
                                                 const unsigned short* __restrict__ ftb,
                                                 unsigned int* __restrict__ h1b) {
    int w = (blockIdx.x * blockDim.x + threadIdx.x) >> 6;   // node
    if (w >= N_NODES) return;
    int lane = threadIdx.x & 63;
    int hh = lane >> 4;
    float erv = er[w * H1 + hh];
    u64 rp = rowp[w];
    int jb = (int)(rp & 0xffffffffu), je = jb + (int)(rp >> 32);
    float ax = 0.f, ay = 0.f, ssum = 0.f;
    int j = jb;
    for (; j + 7 < je; j += 8) {
        int u[8]; float wv[8]; ushort2 f[8];
        #pragma unroll
        for (int k = 0; k < 8; ++k) u[k] = csrp[j + k] & 0xffff;
        #pragma unroll
        for (int k = 0; k < 8; ++k)
            f[k] = *(const ushort2*)(ftb + (size_t)u[k] * HD + lane * 2);
        #pragma unroll
        for (int k = 0; k < 8; ++k) {
            float t = el[u[k] * H1 + hh] + erv;
            t = t > 0.f ? t : SLOPE * t;
            wv[k] = __expf(t);
        }
        #pragma unroll
        for (int k = 0; k < 8; ++k) {
            ax = fmaf(wv[k], bf2f(f[k].x), ax);
            ay = fmaf(wv[k], bf2f(f[k].y), ay);
            ssum += wv[k];
        }
    }
    for (; j < je; ++j) {
        int u0 = csrp[j] & 0xffff;
        float t = el[u0 * H1 + hh] + erv;
        t = t > 0.f ? t : SLOPE * t;
        float w0 = __expf(t);
        ushort2 f0 = *(const ushort2*)(ftb + (size_t)u0 * HD + lane * 2);
        ax = fmaf(w0, bf2f(f0.x), ax); ay = fmaf(w0, bf2f(f0.y), ay);
        ssum += w0;
    }
    float inv = 1.0f / fmaxf(ssum, 1e-9f);
    h1b[(size_t)w * 64 + lane] = (unsigned)f2bf(ax * inv)
                               | ((unsigned)f2bf(ay * inv) << 16);
}

// ---------------------------------------------------------------------------
// BN stats on bf16 h1
// ---------------------------------------------------------------------------
__global__ void bnstats_k(const unsigned short* __restrict__ h1b,
                          float* __restrict__ sums, float* __restrict__ sumsq) {
    int c = threadIdx.x;  // 128 threads
    float acc = 0.f, acc2 = 0.f;
    for (int r = blockIdx.x; r < N_NODES; r += gridDim.x) {
        float v = bf2f(h1b[(size_t)r * HD + c]);
        acc += v; acc2 += v * v;
    }
    atomicAdd(&sums[c], acc);
    atomicAdd(&sumsq[c], acc2);
}

// ---------------------------------------------------------------------------
// layer-2 gather (precomputed exw) fused with log_softmax. Unroll 8.
// ---------------------------------------------------------------------------
__global__ __launch_bounds__(256) void gather2_k(const u64* __restrict__ rowp,
                                                 const unsigned* __restrict__ csrp,
                                                 const float* __restrict__ exw,
                                                 const unsigned short* __restrict__ ft2b,
                                                 float* __restrict__ out) {
    int w = (blockIdx.x * blockDim.x + threadIdx.x) >> 6;   // node
    if (w >= N_NODES) return;
    int lane = threadIdx.x & 63;
    u64 rp = rowp[w];
    int jb = (int)(rp & 0xffffffffu), je = jb + (int)(rp >> 32);
    float acc = 0.f, ssum = 0.f;
    int j = jb;
    for (; j + 7 < je; j += 8) {
        int u[8]; float wv[8]; float fv[8];
        #pragma unroll
        for (int k = 0; k < 8; ++k) u[k] = csrp[j + k] & 0xffff;
        #pragma unroll
        for (int k = 0; k < 8; ++k)
            fv[k] = (lane < NC) ? bf2f(ft2b[(size_t)u[k] * NC + lane]) : 0.f;
        #pragma unroll
        for (int k = 0; k < 8; ++k) wv[k] = exw[j + k];
        #pragma unroll
        for (int k = 0; k < 8; ++k) {
            acc = fmaf(wv[k], fv[k], acc);
            ssum += wv[k];
        }
    }
    for (; j < je; ++j) {
        int u0 = csrp[j] & 0xffff;
        float w0 = exw[j];
        float fa = (lane < NC) ? bf2f(ft2b[(size_t)u0 * NC + lane]) : 0.f;
        acc = fmaf(w0, fa, acc);
        ssum += w0;
    }
    float v = acc / fmaxf(ssum, 1e-9f);
    float vv = (lane < NC) ? v : -INFINITY;
    float m = vv;
    #pragma unroll
    for (int off = 32; off; off >>= 1) m = fmaxf(m, __shfl_xor(m, off));
    float ex2 = (lane < NC) ? __expf(vv - m) : 0.f;
    float sum = ex2;
    #pragma unroll
    for (int off = 32; off; off >>= 1) sum += __shfl_xor(sum, off);
    if (lane < NC) out[(size_t)w * NC + lane] = vv - m - logf(sum);
}

// ---------------------------------------------------------------------------
extern "C" void kernel_launch(void* const* d_in, const int* in_sizes, int n_in,
                              void* d_out, int out_size, void* d_ws, size_t ws_size,
                              hipStream_t stream) {
    const float* x     = (const float*)d_in[0];
    const int*   src   = (const int*)  d_in[1];
    const int*   dst   = (const int*)  d_in[2];
    const float* W1    = (const float*)d_in[3];
    const float* al1   = (const float*)d_in[4];
    const float* ar1   = (const float*)d_in[5];
    const float* gamma = (const float*)d_in[6];
    const float* beta  = (const float*)d_in[7];
    const float* W2    = (const float*)d_in[8];
    const float* al2   = (const float*)d_in[9];
    const float* ar2   = (const float*)d_in[10];
    float* out = (float*)d_out;

    const size_t NSLOT = (size_t)NBIN * BCAP;          // 1,201,152 compact slots
    const size_t NTMP  = (size_t)NBIN * NREP * RCAP;   // 4,003,840 tmp slots

    char* ws = (char*)d_ws;
    size_t o = 0;
    auto allocB = [&](size_t bytes) { void* p = ws + o; o += (bytes + 15) & ~15ull; return p; };
    int*   bincur = (int*)allocB((size_t)NBIN * NREP * 4);   // zeroed by cvtw0_k
    float* bnsum  = (float*)allocB(HD * 4);                  // zeroed by cvtw0_k
    float* bnsq   = (float*)allocB(HD * 4);                  // zeroed by cvtw0_k
    unsigned* tmp  = (unsigned*)allocB(NTMP * 4);
    unsigned* csrp = (unsigned*)allocB(NSLOT * 4);
    int*   bintot  = (int*)allocB(NBIN * 4);
    u64*   rowp    = (u64*)allocB((size_t)N_NODES * 8);
    float* exw2    = (float*)allocB(NSLOT * 4);
    unsigned short* w1t  = (unsigned short*)allocB((size_t)IN_DIM * HD * 2);
    unsigned short* w2t  = (unsigned short*)allocB((size_t)48 * HD * 2);
    unsigned short* ft1b = (unsigned short*)allocB((size_t)N_NODES * HD * 2);
    unsigned int*   h1b  = (unsigned int*)allocB((size_t)N_NODES * HD * 2);
    float* el1  = (float*)allocB(N_NODES * H1 * 4);
    float* er1  = (float*)allocB(N_NODES * H1 * 4);
    unsigned short* ft2b = (unsigned short*)allocB((size_t)N_NODES * NC * 2);
    float* el2  = (float*)allocB(N_NODES * 4);
    float* er2  = (float*)allocB(N_NODES * 4);

    const int NB_S = (int)(NSLOT / 256);               // 4692 (BCAP%256==0)

    // weight cvt + counter zeroing (replaces memset)
    cvtw0_k<<<(IN_DIM * HD + 255) / 256, 256, 0, stream>>>(W1, W2, w1t, w2t,
                                                           bincur, bnsum, bnsq);
    // fused: GEMM1 (+el1/er1 epilogue)  ∥  binscatter
    fusedA_k<<<NB_G + NB_E, 256, 0, stream>>>(x, w1t, al1, ar1, ft1b, el1, er1,
                                              src, dst, bincur, tmp);
    binsort_k<<<NBIN, 256, 0, stream>>>(tmp, bincur, csrp, rowp, bintot);

    gather1_k<<<N_NODES / 4, 256, 0, stream>>>(rowp, csrp, el1, er1, ft1b, h1b);
    bnstats_k<<<512, HD, 0, stream>>>((const unsigned short*)h1b, bnsum, bnsq);

    // GEMM2 (+BN fold+ELU on staging, +el2/er2 epilogue)
    mfma2_k<<<NB_G, 256, 0, stream>>>((const unsigned short*)h1b, w2t,
                                      bnsum, bnsq, gamma, beta, al2, ar2,
                                      ft2b, el2, er2);
    exw2_k<<<NB_S, 256, 0, stream>>>(csrp, bintot, el2, er2, exw2);
    gather2_k<<<N_NODES / 4, 256, 0, stream>>>(rowp, csrp, exw2, ft2b, out);
}

// Round 13
// 320.159 us; speedup vs baseline: 1.1197x; 1.0261x over previous
//
#include <hip/hip_runtime.h>
#include <hip/hip_bf16.h>
#include <math.h>

#define N_NODES 50000
#define N_EDGES 850000
#define IN_DIM  256
#define HD      128      // H1*D
#define H1      4
#define D       32
#define NC      40       // num classes
#define SLOPE   0.2f
#define EPS_BN  1e-5f

#define NBIN    782      // ceil(50000/64) destination bins of 64 nodes
#define BCAP    1536     // compact slots per bin (mean 1088, sigma ~33)
#define NREP    32       // cursor replicas per bin
#define RCAP    160      // slots/(rep,bin): loop cells ~96 mean + headroom
#define NWAVE   4        // waves per 256-thread block (binsort strides by THIS)
#define NB_G    782      // mfma1 tile blocks
#define NB_E2   1661     // binscatter blocks, 512 edges each ((850000+511)/512)

// cell = rep*NBIN + b  (TRANSPOSED): a 64B line = 16 bins of ONE rep; all
// writers of rep r are blocks ≡ r (mod 32) => one XCD => L2-local lines.
// (round 11's b*NREP+rep packed 16 reps/line => cross-XCD ping-pong remained)

typedef __attribute__((ext_vector_type(8))) short bf16x8;
typedef __attribute__((ext_vector_type(4))) float f32x4;
typedef unsigned long long u64;

__device__ __forceinline__ unsigned short f2bf(float x) {
    union { float f; unsigned u; } v; v.f = x;
    unsigned r = v.u + 0x7FFF + ((v.u >> 16) & 1);   // RNE
    return (unsigned short)(r >> 16);
}
__device__ __forceinline__ float bf2f(unsigned short h) {
    union { unsigned u; float f; } v; v.u = ((unsigned)h) << 16;
    return v.f;
}
__device__ __forceinline__ uint4 pack8(float a0,float a1,float a2,float a3,
                                       float a4,float a5,float a6,float a7) {
    uint4 p;
    p.x = f2bf(a0) | ((unsigned)f2bf(a1) << 16);
    p.y = f2bf(a2) | ((unsigned)f2bf(a3) << 16);
    p.z = f2bf(a4) | ((unsigned)f2bf(a5) << 16);
    p.w = f2bf(a6) | ((unsigned)f2bf(a7) << 16);
    return p;
}

// chunk-swizzled [rows][32] bf16 tile: 4 chunks of 8 bf16 per row (64B rows).
__device__ __forceinline__ int tile32_addr(int row, int chunk) {
    return row * 32 + ((chunk ^ ((row >> 1) & 3)) << 3);
}

// ---------------------------------------------------------------------------
// cvtw0: weight cvt/transpose + zero bincur/bnsum/bnsq (replaces memset)
// ---------------------------------------------------------------------------
__global__ void cvtw0_k(const float* __restrict__ W1, const float* __restrict__ W2,
                        unsigned short* __restrict__ W1t, unsigned short* __restrict__ W2t,
                        int* __restrict__ bincur, float* __restrict__ bnsum,
                        float* __restrict__ bnsq) {
    int id = blockIdx.x * blockDim.x + threadIdx.x;
    if (id < IN_DIM * HD) {                 // W1 [256][128] -> W1t [128][256]
        int k = id >> 7, n = id & 127;
        W1t[n * IN_DIM + k] = f2bf(W1[id]);
    }
    if (id < 48 * HD) {                     // W2 [128][40] -> W2t [48][128]
        int n = id >> 7, k = id & 127;
        float v = (n < NC) ? W2[k * NC + n] : 0.f;
        W2t[id] = f2bf(v);
    }
    if (id < NBIN * NREP) bincur[id] = 0;
    if (id < HD) { bnsum[id] = 0.f; bnsq[id] = 0.f; }
}

// ---------------------------------------------------------------------------
// Fused A: blocks [0,NB_G) = MFMA GEMM1 + el1/er1 epilogue;
//          blocks [NB_G, NB_G+NB_E2) = binscatter (2 edges/thread).
// ---------------------------------------------------------------------------
__global__ __launch_bounds__(256) void fusedA_k(const float* __restrict__ X,
                                                const unsigned short* __restrict__ W1t,
                                                const float* __restrict__ al1,
                                                const float* __restrict__ ar1,
                                                unsigned short* __restrict__ ftb,
                                                float* __restrict__ el,
                                                float* __restrict__ er,
                                                const int* __restrict__ src,
                                                const int* __restrict__ dst,
                                                int* __restrict__ bincur,
                                                unsigned* __restrict__ tmp) {
    __shared__ unsigned short alds[2][64 * 32];
    __shared__ unsigned short wlds[2][128 * 32];

    if (blockIdx.x >= NB_G) {
        // ---------------- binscatter path (2 edges/thread) ----------------
        int bb = blockIdx.x - NB_G;
        int rep = bb & (NREP - 1);
        int e0 = bb * 512 + threadIdx.x;
        int e1 = e0 + 256;
        #pragma unroll
        for (int t = 0; t < 2; ++t) {
            int e = t ? e1 : e0;
            if (e < N_EDGES) {
                int v = dst[e];
                int b = v >> 6;
                int cell = rep * NBIN + b;          // transposed layout
                int cur = atomicAdd(&bincur[cell], 1);
                if (cur < RCAP)
                    tmp[(size_t)cell * RCAP + cur] =
                        ((unsigned)(v & 63) << 16) | (unsigned)src[e];
            }
        }
        return;
    }

    // ---------------- mfma1 path ----------------
    const int tid = threadIdx.x;
    const int lane = tid & 63, wid = tid >> 6;
    const int wr = wid >> 1, wc = wid & 1;
    const int rowBase = blockIdx.x * 64;
    const int s_arow = tid >> 2, s_ac = tid & 3;
    const int s_wcol = tid >> 1, s_wc0 = (tid & 1) * 2;

    auto stageA = [&](int buf, int ks) {
        float4 v0 = make_float4(0.f,0.f,0.f,0.f), v1 = v0;
        int gr = rowBase + s_arow;
        if (gr < N_NODES) {
            const float4* p = (const float4*)(X + (size_t)gr * IN_DIM + ks * 32 + s_ac * 8);
            v0 = p[0]; v1 = p[1];
        }
        *(uint4*)&alds[buf][tile32_addr(s_arow, s_ac)] =
            pack8(v0.x,v0.y,v0.z,v0.w,v1.x,v1.y,v1.z,v1.w);
    };
    auto stageW = [&](int buf, int ks) {
        const uint4* g = (const uint4*)(W1t + s_wcol * IN_DIM + ks * 32 + s_wc0 * 8);
        uint4 a = g[0], b = g[1];
        *(uint4*)&wlds[buf][tile32_addr(s_wcol, s_wc0)] = a;
        *(uint4*)&wlds[buf][tile32_addr(s_wcol, s_wc0 + 1)] = b;
    };

    f32x4 acc[2][4];
    #pragma unroll
    for (int mf = 0; mf < 2; ++mf)
        #pragma unroll
        for (int nf = 0; nf < 4; ++nf)
            acc[mf][nf] = (f32x4){0.f, 0.f, 0.f, 0.f};

    stageA(0, 0); stageW(0, 0);
    for (int ks = 0; ks < 8; ++ks) {
        __syncthreads();
        if (ks < 7) { stageA((ks + 1) & 1, ks + 1); stageW((ks + 1) & 1, ks + 1); }
        int buf = ks & 1;
        bf16x8 afrag[2], bfrag[4];
        #pragma unroll
        for (int mf = 0; mf < 2; ++mf) {
            int row = wr * 32 + mf * 16 + (lane & 15);
            afrag[mf] = *(const bf16x8*)&alds[buf][tile32_addr(row, lane >> 4)];
        }
        #pragma unroll
        for (int nf = 0; nf < 4; ++nf) {
            int col = wc * 64 + nf * 16 + (lane & 15);
            bfrag[nf] = *(const bf16x8*)&wlds[buf][tile32_addr(col, lane >> 4)];
        }
        #pragma unroll
        for (int mf = 0; mf < 2; ++mf)
            #pragma unroll
            for (int nf = 0; nf < 4; ++nf)
                acc[mf][nf] = __builtin_amdgcn_mfma_f32_16x16x32_bf16(
                    afrag[mf], bfrag[nf], acc[mf][nf], 0, 0, 0);
    }
    // C write (bf16)
    #pragma unroll
    for (int mf = 0; mf < 2; ++mf) {
        int r0 = rowBase + wr * 32 + mf * 16 + (lane >> 4) * 4;
        #pragma unroll
        for (int nf = 0; nf < 4; ++nf) {
            int col = wc * 64 + nf * 16 + (lane & 15);
            #pragma unroll
            for (int v = 0; v < 4; ++v) {
                int r = r0 + v;
                if (r < N_NODES) ftb[(size_t)r * HD + col] = f2bf(acc[mf][nf][v]);
            }
        }
    }
    // el/er epilogue: this wave's 64 cols = heads {wc*2, wc*2+1} complete.
    float alw[4], arw[4];
    #pragma unroll
    for (int nf = 0; nf < 4; ++nf) {
        int col = wc * 64 + nf * 16 + (lane & 15);
        alw[nf] = al1[(col >> 5) * D + (col & 31)];
        arw[nf] = ar1[(col >> 5) * D + (col & 31)];
    }
    #pragma unroll
    for (int mf = 0; mf < 2; ++mf) {
        #pragma unroll
        for (int v = 0; v < 4; ++v) {
            int r = rowBase + wr * 32 + mf * 16 + (lane >> 4) * 4 + v;
            float elA = acc[mf][0][v] * alw[0] + acc[mf][1][v] * alw[1];
            float erA = acc[mf][0][v] * arw[0] + acc[mf][1][v] * arw[1];
            float elB = acc[mf][2][v] * alw[2] + acc[mf][3][v] * alw[3];
            float erB = acc[mf][2][v] * arw[2] + acc[mf][3][v] * arw[3];
            #pragma unroll
            for (int off = 1; off < 16; off <<= 1) {
                elA += __shfl_xor(elA, off, 16);
                erA += __shfl_xor(erA, off, 16);
                elB += __shfl_xor(elB, off, 16);
                erB += __shfl_xor(erB, off, 16);
            }
            if ((lane & 15) == 0 && r < N_NODES) {
                int hA = wc * 2;
                el[r * H1 + hA]     = elA;  er[r * H1 + hA]     = erA;
                el[r * H1 + hA + 1] = elB;  er[r * H1 + hA + 1] = erB;
            }
        }
    }
}

// ---------------------------------------------------------------------------
// binsort: one block (4 waves) per bin; transposed tmp layout (s*NBIN + b).
// ---------------------------------------------------------------------------
__global__ __launch_bounds__(256) void binsort_k(const unsigned* __restrict__ tmp,
                                                 const int* __restrict__ bincur,
                                                 unsigned* __restrict__ csrp,
                                                 u64* __restrict__ rowp,
                                                 int* __restrict__ bintot) {
    __shared__ int cnts[NREP];
    __shared__ int hist[64];
    __shared__ int cur[64];
    int b = blockIdx.x, tid = threadIdx.x;
    int nbase = b << 6;
    size_t cbase = (size_t)b * BCAP;
    int wv = tid >> 6, ln = tid & 63;
    if (tid < NREP) cnts[tid] = min(bincur[tid * NBIN + b], RCAP);
    if (tid < 64) hist[tid] = 0;
    __syncthreads();
    for (int s = wv; s < NREP; s += NWAVE) {
        int c = cnts[s];
        const unsigned* seg = tmp + (size_t)(s * NBIN + b) * RCAP;
        for (int t = ln; t < c; t += 64)
            atomicAdd(&hist[seg[t] >> 16], 1);
    }
    __syncthreads();
    if (tid < 64) {
        int h = hist[tid];
        int v = h;
        #pragma unroll
        for (int off = 1; off < 64; off <<= 1) {
            int t2 = __shfl_up(v, off);
            if (tid >= off) v += t2;
        }
        int excl = v - h;
        cur[tid] = excl;
        int node = nbase + tid;
        if (node < N_NODES)
            rowp[node] = ((u64)h << 32) | (unsigned)(cbase + excl);
        if (tid == 63) bintot[b] = v;
    }
    __syncthreads();
    for (int s = wv; s < NREP; s += NWAVE) {
        int c = cnts[s];
        const unsigned* seg = tmp + (size_t)(s * NBIN + b) * RCAP;
        for (int t = ln; t < c; t += 64) {
            unsigned p = seg[t];
            int pos = atomicAdd(&cur[p >> 16], 1);
            csrp[cbase + pos] = p;
        }
    }
}

// ---------------------------------------------------------------------------
// MFMA GEMM2 + el2/er2 epilogue: ft2b = bf16( elu(bn(h1b)) @ W2 ).
// ---------------------------------------------------------------------------
__global__ __launch_bounds__(256) void mfma2_k(const unsigned short* __restrict__ Hin,
                                               const unsigned short* __restrict__ W2t,
                                               const float* __restrict__ bnsum,
                                               const float* __restrict__ bnsq,
                                               const float* __restrict__ gamma,
                                               const float* __restrict__ beta,
                                               const float* __restrict__ al2,
                                               const float* __restrict__ ar2,
                                               unsigned short* __restrict__ ft2b,
                                               float* __restrict__ el2,
                                               float* __restrict__ er2) {
    __shared__ unsigned short alds[2][64 * 32];
    __shared__ unsigned short wlds[48 * 128];
    __shared__ float sc_lds[HD], sh_lds[HD];
    const int tid = threadIdx.x;
    const int lane = tid & 63, wid = tid >> 6;
    const int rowBase = blockIdx.x * 64;
    const int s_arow = tid >> 2, s_ac = tid & 3;

    if (tid < HD) {
        const float invN = 1.0f / (float)N_NODES;
        float mu = bnsum[tid] * invN;
        float var = bnsq[tid] * invN - mu * mu;
        float sc = gamma[tid] * rsqrtf(var + EPS_BN);
        sc_lds[tid] = sc;
        sh_lds[tid] = beta[tid] - mu * sc;
    }
    for (int i = tid; i < 48 * 16; i += 256) {
        int col = i >> 4, c = i & 15;
        uint4 v = *(const uint4*)(W2t + col * HD + c * 8);
        *(uint4*)&wlds[col * HD + ((c ^ (col & 7)) << 3)] = v;
    }
    __syncthreads();

    auto stageA = [&](int buf, int ks) {
        int c0 = ks * 32 + s_ac * 8;
        uint4 pv = make_uint4(0,0,0,0);
        int gr = rowBase + s_arow;
        if (gr < N_NODES) pv = *(const uint4*)(Hin + (size_t)gr * HD + c0);
        float4 sc0 = *(const float4*)(sc_lds + c0), sc1 = *(const float4*)(sc_lds + c0 + 4);
        float4 sh0 = *(const float4*)(sh_lds + c0), sh1 = *(const float4*)(sh_lds + c0 + 4);
        float t[8];
        t[0] = fmaf(bf2f(pv.x & 0xffff), sc0.x, sh0.x);
        t[1] = fmaf(bf2f(pv.x >> 16),    sc0.y, sh0.y);
        t[2] = fmaf(bf2f(pv.y & 0xffff), sc0.z, sh0.z);
        t[3] = fmaf(bf2f(pv.y >> 16),    sc0.w, sh0.w);
        t[4] = fmaf(bf2f(pv.z & 0xffff), sc1.x, sh1.x);
        t[5] = fmaf(bf2f(pv.z >> 16),    sc1.y, sh1.y);
        t[6] = fmaf(bf2f(pv.w & 0xffff), sc1.z, sh1.z);
        t[7] = fmaf(bf2f(pv.w >> 16),    sc1.w, sh1.w);
        #pragma unroll
        for (int i = 0; i < 8; ++i) t[i] = t[i] > 0.f ? t[i] : expm1f(t[i]);
        *(uint4*)&alds[buf][tile32_addr(s_arow, s_ac)] =
            pack8(t[0],t[1],t[2],t[3],t[4],t[5],t[6],t[7]);
    };

    f32x4 acc[3];
    #pragma unroll
    for (int nf = 0; nf < 3; ++nf) acc[nf] = (f32x4){0.f, 0.f, 0.f, 0.f};

    stageA(0, 0);
    for (int ks = 0; ks < 4; ++ks) {
        __syncthreads();
        if (ks < 3) stageA((ks + 1) & 1, ks + 1);
        int buf = ks & 1;
        int row = wid * 16 + (lane & 15);
        bf16x8 a = *(const bf16x8*)&alds[buf][tile32_addr(row, lane >> 4)];
        #pragma unroll
        for (int nf = 0; nf < 3; ++nf) {
            int col = nf * 16 + (lane & 15);
            int c = ks * 4 + (lane >> 4);
            bf16x8 b = *(const bf16x8*)&wlds[col * HD + ((c ^ (col & 7)) << 3)];
            acc[nf] = __builtin_amdgcn_mfma_f32_16x16x32_bf16(a, b, acc[nf], 0, 0, 0);
        }
    }
    int r0 = rowBase + wid * 16 + (lane >> 4) * 4;
    #pragma unroll
    for (int nf = 0; nf < 3; ++nf) {
        int col = nf * 16 + (lane & 15);
        if (col < NC) {
            #pragma unroll
            for (int v = 0; v < 4; ++v) {
                int r = r0 + v;
                if (r < N_NODES) ft2b[(size_t)r * NC + col] = f2bf(acc[nf][v]);
            }
        }
    }
    // el2/er2 epilogue: wave holds all 40 (padded 48) cols of its 16 rows.
    float alw2[3], arw2[3];
    #pragma unroll
    for (int nf = 0; nf < 3; ++nf) {
        int col = nf * 16 + (lane & 15);
        alw2[nf] = (col < NC) ? al2[col] : 0.f;
        arw2[nf] = (col < NC) ? ar2[col] : 0.f;
    }
    #pragma unroll
    for (int v = 0; v < 4; ++v) {
        int r = r0 + v;
        float e_l = acc[0][v] * alw2[0] + acc[1][v] * alw2[1] + acc[2][v] * alw2[2];
        float e_r = acc[0][v] * arw2[0] + acc[1][v] * arw2[1] + acc[2][v] * arw2[2];
        #pragma unroll
        for (int off = 1; off < 16; off <<= 1) {
            e_l += __shfl_xor(e_l, off, 16);
            e_r += __shfl_xor(e_r, off, 16);
        }
        if ((lane & 15) == 0 && r < N_NODES) { el2[r] = e_l; er2[r] = e_r; }
    }
}

// ---------------------------------------------------------------------------
// layer-2 edge weights (one exp per edge, coalesced) over bin-slot space
// ---------------------------------------------------------------------------
__global__ void exw2_k(const unsigned* __restrict__ csrp,
                       const int* __restrict__ bintot,
                       const float* __restrict__ el, const float* __restrict__ er,
                       float* __restrict__ exw) {
    int s = blockIdx.x * blockDim.x + threadIdx.x;
    int b = s / BCAP;
    int off = s - b * BCAP;
    if (off >= bintot[b]) return;
    unsigned p = csrp[s];
    float t = el[p & 0xffff] + er[(b << 6) + (p >> 16)];
    t = t > 0.f ? t : SLOPE * t;
    exw[s] = __expf(t);
}

// ---------------------------------------------------------------------------
// layer-1 gather, fused attention weights: one wave per dst node; lane owns
// bf16x2 of 128 dims, head hh = lane>>4. Unroll 8. Writes bf16 h1.
// ---------------------------------------------------------------------------
__global__ __launch_bounds__(256) void gather1_k(const u64* __restrict__ rowp,
                                                 const unsigned* __restrict__ csrp,
                                                 const float* __restrict__ el,
                                                 const float* __restrict__ er,
                                                 const unsigned short* __restrict__ ftb,
                                                 unsigned int* __restrict__ h1b) {
    int w = (blockIdx.x * blockDim.x + threadIdx.x) >> 6;   // node
    if (w >= N_NODES) return;
    int lane = threadIdx.x & 63;
    int hh = lane >> 4;
    float erv = er[w * H1 + hh];
    u64 rp = rowp[w];
    int jb = (int)(rp & 0xffffffffu), je = jb + (int)(rp >> 32);
    float ax = 0.f, ay = 0.f, ssum = 0.f;
    int j = jb;
    for (; j + 7 < je; j += 8) {
        int u[8]; float wv[8]; ushort2 f[8];
        #pragma unroll
        for (int k = 0; k < 8; ++k) u[k] = csrp[j + k] & 0xffff;
        #pragma unroll
        for (int k = 0; k < 8; ++k)
            f[k] = *(const ushort2*)(ftb + (size_t)u[k] * HD + lane * 2);
        #pragma unroll
        for (int k = 0; k < 8; ++k) {
            float t = el[u[k] * H1 + hh] + erv;
            t = t > 0.f ? t : SLOPE * t;
            wv[k] = __expf(t);
        }
        #pragma unroll
        for (int k = 0; k < 8; ++k) {
            ax = fmaf(wv[k], bf2f(f[k].x), ax);
            ay = fmaf(wv[k], bf2f(f[k].y), ay);
            ssum += wv[k];
        }
    }
    for (; j < je; ++j) {
        int u0 = csrp[j] & 0xffff;
        float t = el[u0 * H1 + hh] + erv;
        t = t > 0.f ? t : SLOPE * t;
        float w0 = __expf(t);
        ushort2 f0 = *(const ushort2*)(ftb + (size_t)u0 * HD + lane * 2);
        ax = fmaf(w0, bf2f(f0.x), ax); ay = fmaf(w0, bf2f(f0.y), ay);
        ssum += w0;
    }
    float inv = 1.0f / fmaxf(ssum, 1e-9f);
    h1b[(size_t)w * 64 + lane] = (unsigned)f2bf(ax * inv)
                               | ((unsigned)f2bf(ay * inv) << 16);
}

// ---------------------------------------------------------------------------
// BN stats on bf16 h1
// ---------------------------------------------------------------------------
__global__ void bnstats_k(const unsigned short* __restrict__ h1b,
                          float* __restrict__ sums, float* __restrict__ sumsq) {
    int c = threadIdx.x;  // 128 threads
    float acc = 0.f, acc2 = 0.f;
    for (int r = blockIdx.x; r < N_NODES; r += gridDim.x) {
        float v = bf2f(h1b[(size_t)r * HD + c]);
        acc += v; acc2 += v * v;
    }
    atomicAdd(&sums[c], acc);
    atomicAdd(&sumsq[c], acc2);
}

// ---------------------------------------------------------------------------
// layer-2 gather (precomputed exw) fused with log_softmax. Unroll 8.
// ---------------------------------------------------------------------------
__global__ __launch_bounds__(256) void gather2_k(const u64* __restrict__ rowp,
                                                 const unsigned* __restrict__ csrp,
                                                 const float* __restrict__ exw,
                                                 const unsigned short* __restrict__ ft2b,
                                                 float* __restrict__ out) {
    int w = (blockIdx.x * blockDim.x + threadIdx.x) >> 6;   // node
    if (w >= N_NODES) return;
    int lane = threadIdx.x & 63;
    u64 rp = rowp[w];
    int jb = (int)(rp & 0xffffffffu), je = jb + (int)(rp >> 32);
    float acc = 0.f, ssum = 0.f;
    int j = jb;
    for (; j + 7 < je; j += 8) {
        int u[8]; float wv[8]; float fv[8];
        #pragma unroll
        for (int k = 0; k < 8; ++k) u[k] = csrp[j + k] & 0xffff;
        #pragma unroll
        for (int k = 0; k < 8; ++k)
            fv[k] = (lane < NC) ? bf2f(ft2b[(size_t)u[k] * NC + lane]) : 0.f;
        #pragma unroll
        for (int k = 0; k < 8; ++k) wv[k] = exw[j + k];
        #pragma unroll
        for (int k = 0; k < 8; ++k) {
            acc = fmaf(wv[k], fv[k], acc);
            ssum += wv[k];
        }
    }
    for (; j < je; ++j) {
        int u0 = csrp[j] & 0xffff;
        float w0 = exw[j];
        float fa = (lane < NC) ? bf2f(ft2b[(size_t)u0 * NC + lane]) : 0.f;
        acc = fmaf(w0, fa, acc);
        ssum += w0;
    }
    float v = acc / fmaxf(ssum, 1e-9f);
    float vv = (lane < NC) ? v : -INFINITY;
    float m = vv;
    #pragma unroll
    for (int off = 32; off; off >>= 1) m = fmaxf(m, __shfl_xor(m, off));
    float ex2 = (lane < NC) ? __expf(vv - m) : 0.f;
    float sum = ex2;
    #pragma unroll
    for (int off = 32; off; off >>= 1) sum += __shfl_xor(sum, off);
    if (lane < NC) out[(size_t)w * NC + lane] = vv - m - logf(sum);
}

// ---------------------------------------------------------------------------
extern "C" void kernel_launch(void* const* d_in, const int* in_sizes, int n_in,
                              void* d_out, int out_size, void* d_ws, size_t ws_size,
                              hipStream_t stream) {
    const float* x     = (const float*)d_in[0];
    const int*   src   = (const int*)  d_in[1];
    const int*   dst   = (const int*)  d_in[2];
    const float* W1    = (const float*)d_in[3];
    const float* al1   = (const float*)d_in[4];
    const float* ar1   = (const float*)d_in[5];
    const float* gamma = (const float*)d_in[6];
    const float* beta  = (const float*)d_in[7];
    const float* W2    = (const float*)d_in[8];
    const float* al2   = (const float*)d_in[9];
    const float* ar2   = (const float*)d_in[10];
    float* out = (float*)d_out;

    const size_t NSLOT = (size_t)NBIN * BCAP;          // 1,201,152 compact slots
    const size_t NTMP  = (size_t)NBIN * NREP * RCAP;   // 4,003,840 tmp slots

    char* ws = (char*)d_ws;
    size_t o = 0;
    auto allocB = [&](size_t bytes) { void* p = ws + o; o += (bytes + 15) & ~15ull; return p; };
    int*   bincur = (int*)allocB((size_t)NBIN * NREP * 4);   // zeroed by cvtw0_k
    float* bnsum  = (float*)allocB(HD * 4);                  // zeroed by cvtw0_k
    float* bnsq   = (float*)allocB(HD * 4);                  // zeroed by cvtw0_k
    unsigned* tmp  = (unsigned*)allocB(NTMP * 4);
    unsigned* csrp = (unsigned*)allocB(NSLOT * 4);
    int*   bintot  = (int*)allocB(NBIN * 4);
    u64*   rowp    = (u64*)allocB((size_t)N_NODES * 8);
    float* exw2    = (float*)allocB(NSLOT * 4);
    unsigned short* w1t  = (unsigned short*)allocB((size_t)IN_DIM * HD * 2);
    unsigned short* w2t  = (unsigned short*)allocB((size_t)48 * HD * 2);
    unsigned short* ft1b = (unsigned short*)allocB((size_t)N_NODES * HD * 2);
    unsigned int*   h1b  = (unsigned int*)allocB((size_t)N_NODES * HD * 2);
    float* el1  = (float*)allocB(N_NODES * H1 * 4);
    float* er1  = (float*)allocB(N_NODES * H1 * 4);
    unsigned short* ft2b = (unsigned short*)allocB((size_t)N_NODES * NC * 2);
    float* el2  = (float*)allocB(N_NODES * 4);
    float* er2  = (float*)allocB(N_NODES * 4);

    const int NB_S = (int)(NSLOT / 256);               // 4692 (BCAP%256==0)

    // weight cvt + counter zeroing (replaces memset)
    cvtw0_k<<<(IN_DIM * HD + 255) / 256, 256, 0, stream>>>(W1, W2, w1t, w2t,
                                                           bincur, bnsum, bnsq);
    // fused: GEMM1 (+el1/er1 epilogue)  ∥  binscatter
    fusedA_k<<<NB_G + NB_E2, 256, 0, stream>>>(x, w1t, al1, ar1, ft1b, el1, er1,
                                               src, dst, bincur, tmp);
    binsort_k<<<NBIN, 256, 0, stream>>>(tmp, bincur, csrp, rowp, bintot);

    gather1_k<<<N_NODES / 4, 256, 0, stream>>>(rowp, csrp, el1, er1, ft1b, h1b);
    bnstats_k<<<512, HD, 0, stream>>>((const unsigned short*)h1b, bnsum, bnsq);

    // GEMM2 (+BN fold+ELU on staging, +el2/er2 epilogue)
    mfma2_k<<<NB_G, 256, 0, stream>>>((const unsigned short*)h1b, w2t,
                                      bnsum, bnsq, gamma, beta, al2, ar2,
                                      ft2b, el2, er2);
    exw2_k<<<NB_S, 256, 0, stream>>>(csrp, bintot, el2, er2, exw2);
    gather2_k<<<N_NODES / 4, 256, 0, stream>>>(rowp, csrp, exw2, ft2b, out);
}